// Round 2
// baseline (377.024 us; speedup 1.0000x reference)
//
#include <hip/hip_runtime.h>

typedef __bf16 bf16;
typedef __bf16 bf16x8 __attribute__((ext_vector_type(8)));
typedef float f32x4 __attribute__((ext_vector_type(4)));

#define EPS 1e-8f

constexpr int B = 16, CI = 256, CO = 256, S = 512, H = 64, W = 64;
constexpr int PH = 66;                    // padded spatial dim
constexpr int TAPS = 9;                   // 3x3

// 16-byte "chunks" (8 bf16):
//   wd   chunks: [tap][ci8=32][co=256]    -> UNMODULATED shared weights, 1.18 MB
//   xpad chunks: [b][row=66][ci8=32][col=66] -> style-scaled input, 35.7 MB
constexpr size_t WS_WD    = 0;                            // 1,179,648 B
constexpr size_t WS_XPAD  = 1179648;
constexpr size_t WS_STYLE = WS_XPAD + (size_t)B*PH*32*PH*16;  // [B][CI] f32
constexpr size_t WS_WSQT  = WS_STYLE + 16384;             // [ci][co] f32 = 256 KB
constexpr size_t WS_INV   = WS_WSQT + 262144;             // [B][CO] f32

// ---------------------------------------------------------------- prep1 ----
// blocks 0..255:    wprep  — wts [CO][CI][3][3] f32 -> wd chunks + wsqT
// blocks 256..1279: style  — style[b][c] = y[b]·sw[c] + sb[c]
__global__ void prep1_kernel(const float* __restrict__ y,
                             const float* __restrict__ sw,
                             const float* __restrict__ sb,
                             const float* __restrict__ wts,
                             bf16x8* __restrict__ wd,
                             float* __restrict__ wsqT,
                             float* __restrict__ style) {
    __shared__ float t[8 * 289];   // stride 289: bank-conflict-free gathers
    int i = blockIdx.x;
    if (i < 256) {                 // ---- wprep: 8co x 32ci tile ----
        int cb = i & 31;           // co block 0..31 (8 co each)
        int ib = i >> 5;           // ci block 0..7  (32 ci each)
        const float* src = wts + ((size_t)cb * 8) * (CI * TAPS) + ib * 32 * TAPS;
        for (int e = threadIdx.x; e < 8 * 288; e += 256) {
            int col = e / 288, idx = e - col * 288;        // col = co_l
            t[col * 289 + idx] = src[(size_t)col * (CI * TAPS) + idx];
        }
        __syncthreads();
        // wd chunks: tap(9) x ci8_l(4) x co_l(8) = 288 (strided: 288 > 256)
        for (int c = threadIdx.x; c < 288; c += 256) {
            int co_l = c & 7, ci8_l = (c >> 3) & 3, tap = c >> 5;
            bf16x8 v;
#pragma unroll
            for (int j = 0; j < 8; ++j) v[j] = (bf16)t[co_l * 289 + (ci8_l * 8 + j) * 9 + tap];
            wd[((size_t)tap * 32 + ib * 4 + ci8_l) * CO + cb * 8 + co_l] = v;
        }
        // wsqT: ci_l(32) x co_l(8) = 256
        int c = threadIdx.x;
        int co_l = c & 7, ci_l = c >> 3;
        float s = 0.f;
#pragma unroll
        for (int tap = 0; tap < 9; ++tap) {
            float w = t[co_l * 289 + ci_l * 9 + tap];
            s += w * w;
        }
        wsqT[((size_t)(ib * 32 + ci_l)) * CO + cb * 8 + co_l] = s;
    } else {                       // ---- style: one wave per (b,c) ----
        int i2 = i - 256;
        int b = i2 >> 6;
        int c = (i2 & 63) * 4 + (threadIdx.x >> 6);
        int lane = threadIdx.x & 63;
        const float* yr = y + (size_t)b * S;
        const float* wr = sw + (size_t)c * S;
        float acc = 0.f;
#pragma unroll
        for (int k = 0; k < 8; ++k) acc += yr[lane + k * 64] * wr[lane + k * 64];
        for (int off = 32; off; off >>= 1) acc += __shfl_down(acc, off, 64);
        if (lane == 0) style[b * CI + c] = acc + sb[c];
    }
}

// ---------------------------------------------------------------- prep2 ----
// blocks 0..2175:    xpad   — x * style -> xpad chunks (4 rows x 32 ci each;
//                    yb==16 writes the zero border rows 0 & 65)
// blocks 2176..2191: invstd — rsqrt(sum_ci wsqT[ci][co]*st^2 + EPS)
__global__ void prep2_kernel(const float* __restrict__ x,
                             const float* __restrict__ style,
                             const float* __restrict__ wsqT,
                             bf16x8* __restrict__ xp,
                             float* __restrict__ invstd) {
    __shared__ float t[4][32][W + 1];   // stride 65 words: 2-way (free)
    int i = blockIdx.x;
    if (i >= 2176) {               // ---- invstd ----
        int b = i - 2176, co = threadIdx.x;
        const float* st = style + b * CI;
        float acc = 0.f;
        for (int ci = 0; ci < CI; ++ci) {
            float s = st[ci];
            acc += wsqT[(size_t)ci * CO + co] * s * s;
        }
        invstd[b * CO + co] = rsqrtf(acc + EPS);
        return;
    }
    // ---- xpad ----
    int cc = i & 7;                // ci chunk of 32
    int u = i >> 3;
    int yb = u % 17, b = u / 17;
    bf16x8 z;
#pragma unroll
    for (int j = 0; j < 8; ++j) z[j] = (bf16)0.f;

    if (yb == 16) {                // padded rows 0 and 65: 2 x 4 x 66 chunks
        for (int q = threadIdx.x; q < 2 * 4 * PH; q += 256) {
            int row = (q >= 4 * PH) ? (PH - 1) : 0;
            int rest = (q >= 4 * PH) ? q - 4 * PH : q;
            int sub = rest / PH, col = rest - sub * PH;
            xp[(((size_t)b * PH + row) * 32 + cc * 4 + sub) * PH + col] = z;
        }
        return;
    }

    int h0 = yb * 4;
    const float* xb = x + ((size_t)b * CI + cc * 32) * (H * W);
    const float* st = style + b * CI + cc * 32;
#pragma unroll
    for (int k = 0; k < 8; ++k) {
        int idx = threadIdx.x + k * 256;          // < 2048 float4s
        int w4 = idx & 15, ci = (idx >> 4) & 31, r = idx >> 9;
        f32x4 v = *(const f32x4*)(xb + ((size_t)ci * H + h0 + r) * W + w4 * 4);
        float s = st[ci];
        t[r][ci][w4 * 4 + 0] = v.x * s;
        t[r][ci][w4 * 4 + 1] = v.y * s;
        t[r][ci][w4 * 4 + 2] = v.z * s;
        t[r][ci][w4 * 4 + 3] = v.w * s;
    }
    __syncthreads();
#pragma unroll
    for (int k = 0; k < 4; ++k) {
        int q = threadIdx.x + k * 256;            // < 1024 chunks
        int w = q & 63, sub = (q >> 6) & 3, r = q >> 8;
        bf16x8 v;
#pragma unroll
        for (int j = 0; j < 8; ++j) v[j] = (bf16)t[r][sub * 8 + j][w];
        xp[(((size_t)b * PH + h0 + r + 1) * 32 + cc * 4 + sub) * PH + (w + 1)] = v;
    }
    if (threadIdx.x < 32) {                       // border cols for these rows
        int r = threadIdx.x >> 3, sub = (threadIdx.x >> 1) & 3;
        int col = (threadIdx.x & 1) ? (PH - 1) : 0;
        xp[(((size_t)b * PH + h0 + r + 1) * 32 + cc * 4 + sub) * PH + col] = z;
    }
}

// ----------------------------------------------------------------- conv ----
// Implicit GEMM with SHARED unmodulated weights; demod in epilogue.
// Block 256 thr = 4 waves; block tile 128co x (2 rows x 64 cols);
// wave tile 64co x 64sp = 4x4 mfma_f32_16x16x32_bf16.
// Grid 1D 1024, XCD-pinned: wd (1.18 MB) + one sample slice live per-XCD L2.
//
// ROUND 6: 1-deep register double-buffer of per-tap operands + sched_barrier
// pinning (loads of step s+1 issue above step-s MFMAs; counted vmcnt keeps
// 8 loads in flight).  +8%: ILP win partially offset by the (256,2) TLP cut.
// ROUND 7 change: __launch_bounds__(256,4).  VGPR=84 fits the 128/wave budget
// of 4 waves/SIMD, and the grid is exactly 4 blocks/CU -> whole grid
// co-resident (16 waves/CU).  TLP x2 on top of the retained ILP pipeline.
#define LOAD_TAP(c8_, kh_, kw_, av_, bv_)                                         \
    {                                                                             \
        const bf16x8* wq_ = wbase + ((size_t)((kh_)*3 + (kw_)) * 32 + (c8_)) * CO;\
        const bf16x8* xq_ = xbase + ((size_t)(kh_) * 32 + (c8_)) * PH + (kw_);    \
        _Pragma("unroll") for (int a_ = 0; a_ < 4; ++a_) (av_)[a_] = wq_[a_ * 16];\
        _Pragma("unroll") for (int j_ = 0; j_ < 4; ++j_) (bv_)[j_] = xq_[j_ * 16];\
    }

#define MFMA_STEP(av_, bv_)                                                       \
    _Pragma("unroll") for (int a_ = 0; a_ < 4; ++a_)                              \
        _Pragma("unroll") for (int j_ = 0; j_ < 4; ++j_)                          \
            acc[a_][j_] = __builtin_amdgcn_mfma_f32_16x16x32_bf16(                \
                (av_)[a_], (bv_)[j_], acc[a_][j_], 0, 0, 0);

__global__ __launch_bounds__(256, 4) void conv_kernel(
                            const bf16x8* __restrict__ wd,
                            const bf16x8* __restrict__ xp,
                            const float* __restrict__ bias,
                            const float* __restrict__ invstd,
                            float* __restrict__ out) {
    int i = blockIdx.x;
    int xcd = i & 7, t = i >> 3;               // t: 0..127
    int b = xcd * 2 + (t >> 6);                // one sample at a time per XCD
    int rest = t & 63;
    int cotile = rest & 1, rowpair = rest >> 1;
    int tid = threadIdx.x;
    int wave = tid >> 6, lane = tid & 63;
    int co_half = wave & 1, sp_half = wave >> 1;
    int r = rowpair * 2 + sp_half;             // output row
    int co_base = cotile * 128 + co_half * 64;
    int lm = lane & 15, lk = lane >> 4;

    f32x4 acc[4][4] = {};

    const bf16x8* xpb = xp + (size_t)b * PH * 32 * PH;
    // lane-resolved base pointers; per-step offsets are wave-uniform consts
    const bf16x8* wbase = wd + (size_t)lk * CO + co_base + lm;        // +(tap*32+c8)*CO
    const bf16x8* xbase = xpb + ((size_t)r * 32 + lk) * PH + lm;      // +(kh*32+c8)*PH+kw

    bf16x8 av0[4], bv0[4], av1[4], bv1[4];

    LOAD_TAP(0, 0, 0, av0, bv0);               // prologue: step 0 operands

#pragma unroll 1
    for (int c8a = 0; c8a < 32; c8a += 8) {    // 4 super-iters of 18 steps
#pragma unroll
        for (int v = 0; v < 18; ++v) {
            // current step: half = v/9 (ci8 sub-block), tap = v%9 — all
            // compile-time after unroll.  next-step indices:
            const int ntap = (v + 1) % 9;
            const int nkh = ntap / 3, nkw = ntap % 3;
            int nc8 = (v == 17) ? ((c8a + 8) & 31)          // next super-iter
                                : (c8a + ((v + 1) / 9) * 4); // (wrap load at the
                                                             // very end is dead
                                                             // but in-bounds)
            if ((v & 1) == 0) {
                LOAD_TAP(nc8, nkh, nkw, av1, bv1);
                __builtin_amdgcn_sched_barrier(0);   // loads stay above MFMAs
                MFMA_STEP(av0, bv0);
            } else {
                LOAD_TAP(nc8, nkh, nkw, av0, bv0);
                __builtin_amdgcn_sched_barrier(0);
                MFMA_STEP(av1, bv1);
            }
        }
    }

    // epilogue: D col = lm (spatial, + j*16), row = lk*4 + g (co, + a*16)
#pragma unroll
    for (int a = 0; a < 4; ++a) {
#pragma unroll
        for (int g = 0; g < 4; ++g) {
            int co = co_base + a * 16 + lk * 4 + g;
            float sc = invstd[b * CO + co];
            float bvl = bias[co];
            size_t o = (((size_t)b * CO + co) * H + r) * W;
#pragma unroll
            for (int j = 0; j < 4; ++j)
                out[o + j * 16 + lm] = acc[a][j][g] * sc + bvl;
        }
    }
}

// --------------------------------------------------------------- launch ----
extern "C" void kernel_launch(void* const* d_in, const int* in_sizes, int n_in,
                              void* d_out, int out_size, void* d_ws, size_t ws_size,
                              hipStream_t stream) {
    const float* x    = (const float*)d_in[0];
    const float* y    = (const float*)d_in[1];
    const float* wts  = (const float*)d_in[2];
    const float* bias = (const float*)d_in[3];
    const float* sw   = (const float*)d_in[4];
    const float* sb   = (const float*)d_in[5];
    float* out = (float*)d_out;

    char* ws = (char*)d_ws;
    bf16x8* wd    = (bf16x8*)(ws + WS_WD);
    bf16x8* xpad  = (bf16x8*)(ws + WS_XPAD);
    float* style  = (float*)(ws + WS_STYLE);
    float* wsqT   = (float*)(ws + WS_WSQT);
    float* invstd = (float*)(ws + WS_INV);

    prep1_kernel<<<dim3(1280), dim3(256), 0, stream>>>(y, sw, sb, wts, wd, wsqT, style);
    prep2_kernel<<<dim3(2192), dim3(256), 0, stream>>>(x, style, wsqT, xpad, invstd);
    conv_kernel<<<dim3(1024), dim3(256), 0, stream>>>(wd, xpad, bias, invstd, out);
}

// Round 3
// 191.215 us; speedup vs baseline: 1.9717x; 1.9717x over previous
//
#include <hip/hip_runtime.h>

typedef __bf16 bf16;
typedef __bf16 bf16x8 __attribute__((ext_vector_type(8)));
typedef float f32x4 __attribute__((ext_vector_type(4)));

#define EPS 1e-8f

constexpr int B = 16, CI = 256, CO = 256, S = 512, H = 64, W = 64;
constexpr int PH = 66;                    // padded spatial dim
constexpr int TAPS = 9;                   // 3x3

// 16-byte "chunks" (8 bf16):
//   wd   chunks: [tap][ci8=32][co=256]    -> UNMODULATED shared weights, 1.18 MB
//   xpad chunks: [b][row=66][ci8=32][col=66] -> style-scaled input, 35.7 MB
constexpr size_t WS_WD    = 0;                            // 1,179,648 B
constexpr size_t WS_XPAD  = 1179648;
constexpr size_t WS_STYLE = WS_XPAD + (size_t)B*PH*32*PH*16;  // [B][CI] f32
constexpr size_t WS_WSQT  = WS_STYLE + 16384;             // [ci][co] f32 = 256 KB
constexpr size_t WS_INV   = WS_WSQT + 262144;             // [B][CO] f32

// ---------------------------------------------------------------- prep1 ----
// blocks 0..255:    wprep  — wts [CO][CI][3][3] f32 -> wd chunks + wsqT
// blocks 256..1279: style  — style[b][c] = y[b]·sw[c] + sb[c]
__global__ void prep1_kernel(const float* __restrict__ y,
                             const float* __restrict__ sw,
                             const float* __restrict__ sb,
                             const float* __restrict__ wts,
                             bf16x8* __restrict__ wd,
                             float* __restrict__ wsqT,
                             float* __restrict__ style) {
    __shared__ float t[8 * 289];   // stride 289: bank-conflict-free gathers
    int i = blockIdx.x;
    if (i < 256) {                 // ---- wprep: 8co x 32ci tile ----
        int cb = i & 31;           // co block 0..31 (8 co each)
        int ib = i >> 5;           // ci block 0..7  (32 ci each)
        const float* src = wts + ((size_t)cb * 8) * (CI * TAPS) + ib * 32 * TAPS;
        for (int e = threadIdx.x; e < 8 * 288; e += 256) {
            int col = e / 288, idx = e - col * 288;        // col = co_l
            t[col * 289 + idx] = src[(size_t)col * (CI * TAPS) + idx];
        }
        __syncthreads();
        // wd chunks: tap(9) x ci8_l(4) x co_l(8) = 288 (strided: 288 > 256)
        for (int c = threadIdx.x; c < 288; c += 256) {
            int co_l = c & 7, ci8_l = (c >> 3) & 3, tap = c >> 5;
            bf16x8 v;
#pragma unroll
            for (int j = 0; j < 8; ++j) v[j] = (bf16)t[co_l * 289 + (ci8_l * 8 + j) * 9 + tap];
            wd[((size_t)tap * 32 + ib * 4 + ci8_l) * CO + cb * 8 + co_l] = v;
        }
        // wsqT: ci_l(32) x co_l(8) = 256
        int c = threadIdx.x;
        int co_l = c & 7, ci_l = c >> 3;
        float s = 0.f;
#pragma unroll
        for (int tap = 0; tap < 9; ++tap) {
            float w = t[co_l * 289 + ci_l * 9 + tap];
            s += w * w;
        }
        wsqT[((size_t)(ib * 32 + ci_l)) * CO + cb * 8 + co_l] = s;
    } else {                       // ---- style: one wave per (b,c) ----
        int i2 = i - 256;
        int b = i2 >> 6;
        int c = (i2 & 63) * 4 + (threadIdx.x >> 6);
        int lane = threadIdx.x & 63;
        const float* yr = y + (size_t)b * S;
        const float* wr = sw + (size_t)c * S;
        float acc = 0.f;
#pragma unroll
        for (int k = 0; k < 8; ++k) acc += yr[lane + k * 64] * wr[lane + k * 64];
        for (int off = 32; off; off >>= 1) acc += __shfl_down(acc, off, 64);
        if (lane == 0) style[b * CI + c] = acc + sb[c];
    }
}

// ---------------------------------------------------------------- prep2 ----
// blocks 0..2175:    xpad   — x * style -> xpad chunks (4 rows x 32 ci each;
//                    yb==16 writes the zero border rows 0 & 65)
// blocks 2176..2191: invstd — rsqrt(sum_ci wsqT[ci][co]*st^2 + EPS)
__global__ void prep2_kernel(const float* __restrict__ x,
                             const float* __restrict__ style,
                             const float* __restrict__ wsqT,
                             bf16x8* __restrict__ xp,
                             float* __restrict__ invstd) {
    __shared__ float t[4][32][W + 1];   // stride 65 words: 2-way (free)
    int i = blockIdx.x;
    if (i >= 2176) {               // ---- invstd ----
        int b = i - 2176, co = threadIdx.x;
        const float* st = style + b * CI;
        float acc = 0.f;
        for (int ci = 0; ci < CI; ++ci) {
            float s = st[ci];
            acc += wsqT[(size_t)ci * CO + co] * s * s;
        }
        invstd[b * CO + co] = rsqrtf(acc + EPS);
        return;
    }
    // ---- xpad ----
    int cc = i & 7;                // ci chunk of 32
    int u = i >> 3;
    int yb = u % 17, b = u / 17;
    bf16x8 z;
#pragma unroll
    for (int j = 0; j < 8; ++j) z[j] = (bf16)0.f;

    if (yb == 16) {                // padded rows 0 and 65: 2 x 4 x 66 chunks
        for (int q = threadIdx.x; q < 2 * 4 * PH; q += 256) {
            int row = (q >= 4 * PH) ? (PH - 1) : 0;
            int rest = (q >= 4 * PH) ? q - 4 * PH : q;
            int sub = rest / PH, col = rest - sub * PH;
            xp[(((size_t)b * PH + row) * 32 + cc * 4 + sub) * PH + col] = z;
        }
        return;
    }

    int h0 = yb * 4;
    const float* xb = x + ((size_t)b * CI + cc * 32) * (H * W);
    const float* st = style + b * CI + cc * 32;
#pragma unroll
    for (int k = 0; k < 8; ++k) {
        int idx = threadIdx.x + k * 256;          // < 2048 float4s
        int w4 = idx & 15, ci = (idx >> 4) & 31, r = idx >> 9;
        f32x4 v = *(const f32x4*)(xb + ((size_t)ci * H + h0 + r) * W + w4 * 4);
        float s = st[ci];
        t[r][ci][w4 * 4 + 0] = v.x * s;
        t[r][ci][w4 * 4 + 1] = v.y * s;
        t[r][ci][w4 * 4 + 2] = v.z * s;
        t[r][ci][w4 * 4 + 3] = v.w * s;
    }
    __syncthreads();
#pragma unroll
    for (int k = 0; k < 4; ++k) {
        int q = threadIdx.x + k * 256;            // < 1024 chunks
        int w = q & 63, sub = (q >> 6) & 3, r = q >> 8;
        bf16x8 v;
#pragma unroll
        for (int j = 0; j < 8; ++j) v[j] = (bf16)t[r][sub * 8 + j][w];
        xp[(((size_t)b * PH + h0 + r + 1) * 32 + cc * 4 + sub) * PH + (w + 1)] = v;
    }
    if (threadIdx.x < 32) {                       // border cols for these rows
        int r = threadIdx.x >> 3, sub = (threadIdx.x >> 1) & 3;
        int col = (threadIdx.x & 1) ? (PH - 1) : 0;
        xp[(((size_t)b * PH + h0 + r + 1) * 32 + cc * 4 + sub) * PH + col] = z;
    }
}

// ----------------------------------------------------------------- conv ----
// Implicit GEMM with SHARED unmodulated weights; demod in epilogue.
// Block 256 thr = 4 waves; block tile 128co x (4 rows x 64 cols);
// wave tile 64co x (2 rows x 64 cols) = 4x8 mfma_f32_16x16x32_bf16.
// Grid 1D 512 = exactly 2 blocks/CU, whole grid co-resident at (256,2).
//
// ROUND 6: 1-deep register double-buffer of per-tap operands + sched_barrier.
// ROUND 7 FAILED: (256,4) halved the VGPR budget to 128 -> allocator spilled
//   (VGPR=64, WRITE_SIZE 65->376 MB scratch, MfmaUtil 12%).  TLP and ILP
//   compete for the register file; this pipeline needs the 256-reg budget.
// ROUND 8 change: spend the (256,2) budget on DEEPER ILP instead of waves.
//   Wave tile 64co x 128sp: 32 MFMAs (~155 cyc) per step vs ~200 cyc L2
//   latency, 12 loads/step, still 1-step-ahead double-buffered.
//   acc 128 + av bufs 32 + bv bufs 64 + addressing ~= 245 regs.
#define LOAD_TAP(c8_, kh_, kw_, av_, bv_)                                         \
    {                                                                             \
        const bf16x8* wq_ = wbase + ((size_t)((kh_)*3 + (kw_)) * 32 + (c8_)) * CO;\
        const bf16x8* xq_ = xbase + ((size_t)(kh_) * 32 * PH + (size_t)(c8_) * PH + (kw_)); \
        _Pragma("unroll") for (int a_ = 0; a_ < 4; ++a_) (av_)[a_] = wq_[a_ * 16];\
        _Pragma("unroll") for (int jr_ = 0; jr_ < 2; ++jr_)                       \
            _Pragma("unroll") for (int jc_ = 0; jc_ < 4; ++jc_)                   \
                (bv_)[jr_ * 4 + jc_] = xq_[(size_t)jr_ * 32 * PH + jc_ * 16];     \
    }

#define MFMA_STEP(av_, bv_)                                                       \
    _Pragma("unroll") for (int a_ = 0; a_ < 4; ++a_)                              \
        _Pragma("unroll") for (int j_ = 0; j_ < 8; ++j_)                          \
            acc[a_][j_] = __builtin_amdgcn_mfma_f32_16x16x32_bf16(                \
                (av_)[a_], (bv_)[j_], acc[a_][j_], 0, 0, 0);

__global__ __launch_bounds__(256, 2) void conv_kernel(
                            const bf16x8* __restrict__ wd,
                            const bf16x8* __restrict__ xp,
                            const float* __restrict__ bias,
                            const float* __restrict__ invstd,
                            float* __restrict__ out) {
    int i = blockIdx.x;
    int xcd = i & 7, t = i >> 3;               // t: 0..63
    int b = xcd * 2 + (t >> 5);                // 2 samples per XCD
    int rest = t & 31;
    int cotile = rest & 1, rowquad = rest >> 1; // 16 row-quads of 4 rows
    int tid = threadIdx.x;
    int wave = tid >> 6, lane = tid & 63;
    int co_half = wave & 1, sp_half = wave >> 1;
    int r0 = rowquad * 4 + sp_half * 2;        // wave's first output row (+jr)
    int co_base = cotile * 128 + co_half * 64;
    int lm = lane & 15, lk = lane >> 4;

    f32x4 acc[4][8] = {};

    const bf16x8* xpb = xp + (size_t)b * PH * 32 * PH;
    // lane-resolved base pointers; per-step offsets are wave-uniform consts
    const bf16x8* wbase = wd + (size_t)lk * CO + co_base + lm;        // +(tap*32+c8)*CO
    const bf16x8* xbase = xpb + ((size_t)r0 * 32 + lk) * PH + lm;     // +(kh*32+c8)*PH+kw (+jr*32*PH)

    bf16x8 av0[4], bv0[8], av1[4], bv1[8];

    LOAD_TAP(0, 0, 0, av0, bv0);               // prologue: step 0 operands

#pragma unroll 1
    for (int c8a = 0; c8a < 32; c8a += 8) {    // 4 super-iters of 18 steps
#pragma unroll
        for (int v = 0; v < 18; ++v) {
            // current step: half = v/9 (ci8 sub-block), tap = v%9 — all
            // compile-time after unroll.  next-step indices:
            const int ntap = (v + 1) % 9;
            const int nkh = ntap / 3, nkw = ntap % 3;
            int nc8 = (v == 17) ? ((c8a + 8) & 31)          // next super-iter
                                : (c8a + ((v + 1) / 9) * 4); // (wrap load at the
                                                             // very end is dead
                                                             // but in-bounds)
            if ((v & 1) == 0) {
                LOAD_TAP(nc8, nkh, nkw, av1, bv1);
                __builtin_amdgcn_sched_barrier(0);   // loads stay above MFMAs
                MFMA_STEP(av0, bv0);
            } else {
                LOAD_TAP(nc8, nkh, nkw, av0, bv0);
                __builtin_amdgcn_sched_barrier(0);
                MFMA_STEP(av1, bv1);
            }
        }
    }

    // epilogue: D col = lm (spatial, + jc*16), row = lk*4 + g (co, + a*16)
#pragma unroll
    for (int a = 0; a < 4; ++a) {
#pragma unroll
        for (int g = 0; g < 4; ++g) {
            int co = co_base + a * 16 + lk * 4 + g;
            float sc = invstd[b * CO + co];
            float bvl = bias[co];
#pragma unroll
            for (int jr = 0; jr < 2; ++jr) {
                size_t o = (((size_t)b * CO + co) * H + r0 + jr) * W;
#pragma unroll
                for (int jc = 0; jc < 4; ++jc)
                    out[o + jc * 16 + lm] = acc[a][jr * 4 + jc][g] * sc + bvl;
            }
        }
    }
}

// --------------------------------------------------------------- launch ----
extern "C" void kernel_launch(void* const* d_in, const int* in_sizes, int n_in,
                              void* d_out, int out_size, void* d_ws, size_t ws_size,
                              hipStream_t stream) {
    const float* x    = (const float*)d_in[0];
    const float* y    = (const float*)d_in[1];
    const float* wts  = (const float*)d_in[2];
    const float* bias = (const float*)d_in[3];
    const float* sw   = (const float*)d_in[4];
    const float* sb   = (const float*)d_in[5];
    float* out = (float*)d_out;

    char* ws = (char*)d_ws;
    bf16x8* wd    = (bf16x8*)(ws + WS_WD);
    bf16x8* xpad  = (bf16x8*)(ws + WS_XPAD);
    float* style  = (float*)(ws + WS_STYLE);
    float* wsqT   = (float*)(ws + WS_WSQT);
    float* invstd = (float*)(ws + WS_INV);

    prep1_kernel<<<dim3(1280), dim3(256), 0, stream>>>(y, sw, sb, wts, wd, wsqT, style);
    prep2_kernel<<<dim3(2192), dim3(256), 0, stream>>>(x, style, wsqT, xpad, invstd);
    conv_kernel<<<dim3(512), dim3(256), 0, stream>>>(wd, xpad, bias, invstd, out);
}